// Round 1
// baseline (34747.522 us; speedup 1.0000x reference)
//
#include <hip/hip_runtime.h>
#include <hip/hip_cooperative_groups.h>

namespace cg = cooperative_groups;

using u16 = unsigned short;
typedef __attribute__((ext_vector_type(8))) __bf16 bf16x8;
typedef __attribute__((ext_vector_type(8))) short s16x8;
typedef __attribute__((ext_vector_type(4))) float f32x4;

static_assert(sizeof(bf16x8) == 16, "bf16x8 must be 16B");

// ---------- helpers ----------
__device__ __forceinline__ u16 f2bf(float f) {
    unsigned int u = __float_as_uint(f);
    u = (u + 0x7FFFu + ((u >> 16) & 1u)) >> 16;
    return (u16)u;
}
__device__ __forceinline__ float bf2f(u16 v) {
    return __uint_as_float(((unsigned int)v) << 16);
}
__device__ __forceinline__ bf16x8 load8(const u16* p) {
    s16x8 v = *reinterpret_cast<const s16x8*>(p);
    return __builtin_bit_cast(bf16x8, v);
}
__device__ __forceinline__ f32x4 mfma16(bf16x8 a, bf16x8 b, f32x4 c) {
    return __builtin_amdgcn_mfma_f32_16x16x32_bf16(a, b, c, 0, 0, 0);
}
__device__ __forceinline__ void gl_lds16(const void* g, void* s) {
    __builtin_amdgcn_global_load_lds((const __attribute__((address_space(1))) void*)g,
                                     (__attribute__((address_space(3))) void*)s, 16, 0, 0);
}
__device__ __forceinline__ float sigm(float x) { return 1.f / (1.f + __expf(-x)); }
__device__ __forceinline__ float tanh_(float x) {
    const float a = __expf(-2.f * fabsf(x));
    const float t = (1.f - a) / (1.f + a);
    return x >= 0.f ? t : -t;
}

// ---------- sizes ----------
#define T_SEQ 512
#define B_SZ  8
#define H_SZ  1024
#define NG    4096   // 4*H
#define M_SZ  4096   // B*T

// ws byte offsets
#define O_PARAMS 0ull
#define O_XBF    1048576ull
#define O_WIH0F  9437184ull
#define O_WIH0R  17825792ull
#define O_WIH1F  26214400ull
#define O_WIH1R  42991616ull
#define O_WHH0F  59768832ull
#define O_WHH0R  68157440ull
#define O_WHH1F  76546048ull
#define O_WHH1R  84934656ull
#define O_XG     93323264ull   // [2][512][8][4096] bf16  (z overlays this later)
#define O_Y      160432128ull  // [8][512][2048] bf16
#define O_X1     177209344ull  // [4096][2048] bf16
#define O_T0     193986560ull  // [4096][64] bf16
#define O_HBUF   194510848ull  // [2][2][16][1024] bf16
#define O_H0S    194641920ull  // [2][8][1024] f32
#define O_C0S    194707456ull  // [2][8][1024] f32

// ---------- hypernetwork matvec + slice to bf16 ----------
__global__ void k_params(const float* __restrict__ hw, const float* __restrict__ emb,
                         const int* __restrict__ lid, u16* __restrict__ pout) {
    const int i = blockIdx.x * 256 + threadIdx.x;   // < 524288
    const float* e = emb + lid[0] * 32;
    const float* w = hw + (size_t)i * 32;
    float s = 0.f;
#pragma unroll
    for (int k = 0; k < 32; ++k) s += w[k] * e[k];
    pout[i] = f2bf(s);
}

// ---------- f32 -> bf16 conversion (float4-wide) ----------
__global__ void k_cvt(const float* __restrict__ in, u16* __restrict__ out, int n4) {
    const int i = blockIdx.x * 256 + threadIdx.x;
    if (i >= n4) return;
    const float4 v = ((const float4*)in)[i];
    ushort4 o;
    o.x = f2bf(v.x); o.y = f2bf(v.y); o.z = f2bf(v.z); o.w = f2bf(v.w);
    ((ushort4*)out)[i] = o;
}

// ---------- input-projection GEMM: Xg[t][b][n] = A[m]·Bw[n] + bih[n]+bhh[n] ----------
// A: (4096 x K) bf16 row-major (m = b*512+t), Bw: (4096 x K) bf16 row-major.
template <int K>
__global__ __launch_bounds__(256, 2)
void k_gemm_xg(const u16* __restrict__ A, const u16* __restrict__ Bw,
               const float* __restrict__ bih, const float* __restrict__ bhh,
               u16* __restrict__ Xg) {
    __shared__ __align__(16) u16 Al[128 * 32];
    __shared__ __align__(16) u16 Bl[128 * 32];
    const int tid = threadIdx.x;
    const int wv = tid >> 6, l = tid & 63;
    const int m0 = blockIdx.x * 128, n0 = blockIdx.y * 128;
    const int wr = (wv >> 1) * 64, wc = (wv & 1) * 64;
    const int r8 = l >> 2;          // 0..15
    const int c8 = (l & 3) * 8;     // 0,8,16,24
    f32x4 acc[4][4] = {};

    for (int k0 = 0; k0 < K; k0 += 32) {
#pragma unroll
        for (int q = 0; q < 2; ++q) {
            const int inst = wv * 2 + q;
            const int row = inst * 16 + r8;
            gl_lds16(A + (size_t)(m0 + row) * K + k0 + c8, (void*)(Al + inst * 512));
            gl_lds16(Bw + (size_t)(n0 + row) * K + k0 + c8, (void*)(Bl + inst * 512));
        }
        __syncthreads();
        bf16x8 af[4], bfv[4];
#pragma unroll
        for (int i = 0; i < 4; ++i) {
            af[i]  = load8(&Al[(wr + i * 16 + (l & 15)) * 32 + ((l >> 4) * 8)]);
            bfv[i] = load8(&Bl[(wc + i * 16 + (l & 15)) * 32 + ((l >> 4) * 8)]);
        }
#pragma unroll
        for (int i = 0; i < 4; ++i)
#pragma unroll
            for (int j = 0; j < 4; ++j)
                acc[i][j] = mfma16(af[i], bfv[j], acc[i][j]);
        __syncthreads();
    }
    const int b = m0 >> 9;   // uniform per block
#pragma unroll
    for (int i = 0; i < 4; ++i)
#pragma unroll
        for (int j = 0; j < 4; ++j)
#pragma unroll
            for (int r = 0; r < 4; ++r) {
                const int m = m0 + wr + i * 16 + (l >> 4) * 4 + r;
                const int n = n0 + wc + j * 16 + (l & 15);
                const int t = m & 511;
                const float v = acc[i][j][r] + bih[n] + bhh[n];
                Xg[((size_t)(t * 8 + b)) * 4096 + n] = f2bf(v);
            }
}

// ---------- persistent bi-LSTM recurrence (cooperative) ----------
// 256 WGs: WGs [0,128) forward, [128,256) reverse. Each WG owns 8 h-columns.
__global__ __launch_bounds__(256, 1)
void k_lstm(const u16* __restrict__ Xg,     // [2][512][8][4096] bf16
            const u16* __restrict__ WhhF, const u16* __restrict__ WhhR,  // 4096x1024 bf16
            const float* __restrict__ h0, const float* __restrict__ c0,  // [2][8][1024]
            int has_init,
            u16* __restrict__ hbuf,         // [2][2][16][1024] bf16 (dbuf)
            u16* __restrict__ y,            // [8][512][2048] bf16
            float* __restrict__ hfin, float* __restrict__ cfin) {        // [2][8][1024]
    cg::grid_group grid = cg::this_grid();
    const int wg = blockIdx.x;
    const int dir = wg >> 7;
    const int j0 = (wg & 127) * 8;
    const int tid = threadIdx.x;
    const int wv = tid >> 6, l = tid & 63;
    const int kh = wv >> 1, nt = wv & 1;
    __shared__ __align__(16) float gpart[4][16][16];   // [wave][gate-col][batch-row]

    const u16* Whh = dir ? WhhR : WhhF;
    // persistent B-fragments: this wave's 16 gate columns x its K-half, in VGPRs
    bf16x8 bfr[16];
    {
        const int idx = nt * 16 + (l & 15);
        const size_t rowb = (size_t)((idx >> 3) * 1024 + j0 + (idx & 7)) * 1024;
        const int kb = kh * 512 + ((l >> 4) * 8);
#pragma unroll
        for (int m = 0; m < 16; ++m) bfr[m] = load8(Whh + rowb + kb + m * 32);
    }
    const int jj = l & 7, bb = l >> 3;
    float c_r = 0.f;
    if (wv == 0) {
        float hinit = 0.f;
        if (has_init) {
            c_r   = c0[dir * 8192 + bb * 1024 + j0 + jj];
            hinit = h0[dir * 8192 + bb * 1024 + j0 + jj];
        }
        hbuf[dir * 32768 + bb * 1024 + j0 + jj] = f2bf(hinit);
    }
    grid.sync();

    const size_t xg_dir = (size_t)dir * T_SEQ * 8 * 4096;
    for (int t = 0; t < T_SEQ; ++t) {
        const int rd = t & 1;
        const int tt = dir ? (T_SEQ - 1 - t) : t;
        // A-fragments: full h from the read buffer (rows 8..15 are pad, harmless)
        const u16* hb = hbuf + dir * 32768 + rd * 16384 + (size_t)(l & 15) * 1024 + kh * 512 + ((l >> 4) * 8);
        bf16x8 afr[16];
#pragma unroll
        for (int m = 0; m < 16; ++m) afr[m] = load8(hb + m * 32);
        f32x4 acc = {0.f, 0.f, 0.f, 0.f};
#pragma unroll
        for (int m = 0; m < 16; ++m) acc = mfma16(afr[m], bfr[m], acc);
        *reinterpret_cast<f32x4*>(&gpart[wv][l & 15][(l >> 4) * 4]) = acc;
        __syncthreads();
        if (wv == 0) {
            const u16* xr = Xg + xg_dir + ((size_t)tt * 8 + bb) * 4096 + j0 + jj;
            const float gi = gpart[0][jj][bb]     + gpart[2][jj][bb]     + bf2f(xr[0]);
            const float gf = gpart[0][8 + jj][bb] + gpart[2][8 + jj][bb] + bf2f(xr[1024]);
            const float gg = gpart[1][jj][bb]     + gpart[3][jj][bb]     + bf2f(xr[2048]);
            const float go = gpart[1][8 + jj][bb] + gpart[3][8 + jj][bb] + bf2f(xr[3072]);
            const float i_ = sigm(gi), f_ = sigm(gf), g_ = tanh_(gg), o_ = sigm(go);
            c_r = f_ * c_r + i_ * g_;
            const float h_ = o_ * tanh_(c_r);
            const u16 h16 = f2bf(h_);
            hbuf[dir * 32768 + (rd ^ 1) * 16384 + bb * 1024 + j0 + jj] = h16;
            y[(size_t)bb * (T_SEQ * 2048) + (size_t)tt * 2048 + dir * 1024 + j0 + jj] = h16;
            if (t == T_SEQ - 1) {
                hfin[dir * 8192 + bb * 1024 + j0 + jj] = h_;
                cfin[dir * 8192 + bb * 1024 + j0 + jj] = c_r;
            }
        }
        grid.sync();
    }
}

// ---------- adapter GEMM1: t0 = relu(y @ w_down^T), (4096 x 64), K=2048 ----------
__global__ __launch_bounds__(64, 1)
void k_adp1(const u16* __restrict__ y, const u16* __restrict__ wd, u16* __restrict__ t0) {
    const int l = threadIdx.x;
    const int m0 = blockIdx.x * 16;
    const int ko = (l >> 4) * 8;
    f32x4 acc[4] = {};
    for (int k = 0; k < 2048; k += 32) {
        const bf16x8 a = load8(y + (size_t)(m0 + (l & 15)) * 2048 + k + ko);
#pragma unroll
        for (int ni = 0; ni < 4; ++ni) {
            const bf16x8 b = load8(wd + (size_t)(ni * 16 + (l & 15)) * 2048 + k + ko);
            acc[ni] = mfma16(a, b, acc[ni]);
        }
    }
#pragma unroll
    for (int ni = 0; ni < 4; ++ni)
#pragma unroll
        for (int r = 0; r < 4; ++r) {
            const int m = m0 + (l >> 4) * 4 + r;
            const int n = ni * 16 + (l & 15);
            t0[(size_t)m * 64 + n] = f2bf(fmaxf(acc[ni][r], 0.f));
        }
}

// ---------- adapter GEMM2: z = t0 @ w_up^T, (4096 x 2048), K=64 ----------
__global__ __launch_bounds__(256, 2)
void k_adp2(const u16* __restrict__ t0, const u16* __restrict__ wu, float* __restrict__ z) {
    const int tid = threadIdx.x, wv = tid >> 6, l = tid & 63;
    const int m0 = blockIdx.x * 64 + wv * 16;
    const int n0 = blockIdx.y * 128;
    const int ko = (l >> 4) * 8;
    const bf16x8 a0 = load8(t0 + (size_t)(m0 + (l & 15)) * 64 + ko);
    const bf16x8 a1 = load8(t0 + (size_t)(m0 + (l & 15)) * 64 + 32 + ko);
#pragma unroll
    for (int ni = 0; ni < 8; ++ni) {
        const int n = n0 + ni * 16;
        const bf16x8 b0 = load8(wu + (size_t)(n + (l & 15)) * 64 + ko);
        const bf16x8 b1 = load8(wu + (size_t)(n + (l & 15)) * 64 + 32 + ko);
        f32x4 c = {0.f, 0.f, 0.f, 0.f};
        c = mfma16(a0, b0, c);
        c = mfma16(a1, b1, c);
#pragma unroll
        for (int r = 0; r < 4; ++r)
            z[(size_t)(m0 + (l >> 4) * 4 + r) * 2048 + n + (l & 15)] = c[r];
    }
}

// ---------- LayerNorm over 2048, optional bf16 output ----------
template <int BF16OUT>
__global__ __launch_bounds__(256, 4)
void k_ln(const float* __restrict__ z, const float* __restrict__ g,
          const float* __restrict__ be, void* __restrict__ out) {
    const int row = blockIdx.x, tid = threadIdx.x;
    const float* zr = z + (size_t)row * 2048;
    const float4 v0 = ((const float4*)zr)[tid * 2];
    const float4 v1 = ((const float4*)zr)[tid * 2 + 1];
    float o[8] = {v0.x, v0.y, v0.z, v0.w, v1.x, v1.y, v1.z, v1.w};
    float s = 0.f, q = 0.f;
#pragma unroll
    for (int i = 0; i < 8; ++i) { s += o[i]; q += o[i] * o[i]; }
#pragma unroll
    for (int off = 32; off > 0; off >>= 1) { s += __shfl_xor(s, off); q += __shfl_xor(q, off); }
    __shared__ float sm[8];
    const int wv = tid >> 6;
    if ((tid & 63) == 0) { sm[wv] = s; sm[4 + wv] = q; }
    __syncthreads();
    const float stot = sm[0] + sm[1] + sm[2] + sm[3];
    const float qtot = sm[4] + sm[5] + sm[6] + sm[7];
    const float mean = stot * (1.f / 2048.f);
    const float var = qtot * (1.f / 2048.f) - mean * mean;
    const float rs = rsqrtf(var + 1e-5f);
    const int c = tid * 8;
#pragma unroll
    for (int i = 0; i < 8; ++i) o[i] = (o[i] - mean) * rs * g[c + i] + be[c + i];
    if (BF16OUT) {
        u16* ob = (u16*)out + (size_t)row * 2048 + c;
#pragma unroll
        for (int i = 0; i < 8; ++i) ob[i] = f2bf(o[i]);
    } else {
        float* of = (float*)out + (size_t)row * 2048 + c;
        ((float4*)of)[0] = make_float4(o[0], o[1], o[2], o[3]);
        ((float4*)of)[1] = make_float4(o[4], o[5], o[6], o[7]);
    }
}

// ---------- host ----------
static inline void cvt_launch(const float* src, u16* dst, int n, hipStream_t s) {
    const int n4 = n / 4;
    k_cvt<<<(n4 + 255) / 256, 256, 0, s>>>(src, dst, n4);
}

extern "C" void kernel_launch(void* const* d_in, const int* in_sizes, int n_in,
                              void* d_out, int out_size, void* d_ws, size_t ws_size,
                              hipStream_t stream) {
    const float* x     = (const float*)d_in[0];
    const float* lemb  = (const float*)d_in[1];
    const float* hw    = (const float*)d_in[2];
    const float* wih0f = (const float*)d_in[3];
    const float* whh0f = (const float*)d_in[4];
    const float* bih0f = (const float*)d_in[5];
    const float* bhh0f = (const float*)d_in[6];
    const float* wih0r = (const float*)d_in[7];
    const float* whh0r = (const float*)d_in[8];
    const float* bih0r = (const float*)d_in[9];
    const float* bhh0r = (const float*)d_in[10];
    const float* lng0  = (const float*)d_in[11];
    const float* lnb0  = (const float*)d_in[12];
    const float* wih1f = (const float*)d_in[13];
    const float* whh1f = (const float*)d_in[14];
    const float* bih1f = (const float*)d_in[15];
    const float* bhh1f = (const float*)d_in[16];
    const float* wih1r = (const float*)d_in[17];
    const float* whh1r = (const float*)d_in[18];
    const float* bih1r = (const float*)d_in[19];
    const float* bhh1r = (const float*)d_in[20];
    const float* lng1  = (const float*)d_in[21];
    const float* lnb1  = (const float*)d_in[22];
    const int*   lid   = (const int*)d_in[23];

    char* ws = (char*)d_ws;
    u16* p_params = (u16*)(ws + O_PARAMS);
    u16* p_xbf    = (u16*)(ws + O_XBF);
    u16* p_wih0f  = (u16*)(ws + O_WIH0F);
    u16* p_wih0r  = (u16*)(ws + O_WIH0R);
    u16* p_wih1f  = (u16*)(ws + O_WIH1F);
    u16* p_wih1r  = (u16*)(ws + O_WIH1R);
    u16* p_whh0f  = (u16*)(ws + O_WHH0F);
    u16* p_whh0r  = (u16*)(ws + O_WHH0R);
    u16* p_whh1f  = (u16*)(ws + O_WHH1F);
    u16* p_whh1r  = (u16*)(ws + O_WHH1R);
    u16* p_xg     = (u16*)(ws + O_XG);
    u16* p_y      = (u16*)(ws + O_Y);
    u16* p_x1     = (u16*)(ws + O_X1);
    u16* p_t0     = (u16*)(ws + O_T0);
    u16* p_hbuf   = (u16*)(ws + O_HBUF);
    float* p_h0s  = (float*)(ws + O_H0S);
    float* p_c0s  = (float*)(ws + O_C0S);
    float* p_z    = (float*)(ws + O_XG);   // overlays Xg (dead when z is live)

    float* outx = (float*)d_out;
    float* outh = outx + 8 * 512 * 2048;
    float* outc = outh + 2 * 8 * 1024;

    // 1. hypernetwork params -> bf16 adapters
    k_params<<<2048, 256, 0, stream>>>(hw, lemb, lid, p_params);
    // 2. conversions to bf16
    cvt_launch(x, p_xbf, 4194304, stream);
    cvt_launch(wih0f, p_wih0f, 4194304, stream);
    cvt_launch(wih0r, p_wih0r, 4194304, stream);
    cvt_launch(wih1f, p_wih1f, 8388608, stream);
    cvt_launch(wih1r, p_wih1r, 8388608, stream);
    cvt_launch(whh0f, p_whh0f, 4194304, stream);
    cvt_launch(whh0r, p_whh0r, 4194304, stream);
    cvt_launch(whh1f, p_whh1f, 4194304, stream);
    cvt_launch(whh1r, p_whh1r, 4194304, stream);

    // 3. layer 0 input projections (f and r)
    k_gemm_xg<1024><<<dim3(32, 32), 256, 0, stream>>>(p_xbf, p_wih0f, bih0f, bhh0f, p_xg);
    k_gemm_xg<1024><<<dim3(32, 32), 256, 0, stream>>>(p_xbf, p_wih0r, bih0r, bhh0r, p_xg + 16777216);

    // 4. layer 0 recurrence (cooperative)
    {
        const u16* xg_c = p_xg; const u16* wf = p_whh0f; const u16* wr = p_whh0r;
        const float* h0p = p_h0s; const float* c0p = p_c0s; int has = 0;
        u16* hb = p_hbuf; u16* yy = p_y; float* hf = p_h0s; float* cf = p_c0s;
        void* args[] = {&xg_c, &wf, &wr, &h0p, &c0p, &has, &hb, &yy, &hf, &cf};
        hipLaunchCooperativeKernel((void*)k_lstm, dim3(256), dim3(256), args, 0, stream);
    }

    // 5. adapter 0 + LN -> x1 (bf16)
    k_adp1<<<256, 64, 0, stream>>>(p_y, p_params, p_t0);
    k_adp2<<<dim3(64, 16), 256, 0, stream>>>(p_t0, p_params + 131072, p_z);
    k_ln<1><<<4096, 256, 0, stream>>>(p_z, lng0, lnb0, (void*)p_x1);

    // 6. layer 1 input projections
    k_gemm_xg<2048><<<dim3(32, 32), 256, 0, stream>>>(p_x1, p_wih1f, bih1f, bhh1f, p_xg);
    k_gemm_xg<2048><<<dim3(32, 32), 256, 0, stream>>>(p_x1, p_wih1r, bih1r, bhh1r, p_xg + 16777216);

    // 7. layer 1 recurrence (initial state = layer 0 finals), finals -> d_out
    {
        const u16* xg_c = p_xg; const u16* wf = p_whh1f; const u16* wr = p_whh1r;
        const float* h0p = p_h0s; const float* c0p = p_c0s; int has = 1;
        u16* hb = p_hbuf; u16* yy = p_y; float* hf = outh; float* cf = outc;
        void* args[] = {&xg_c, &wf, &wr, &h0p, &c0p, &has, &hb, &yy, &hf, &cf};
        hipLaunchCooperativeKernel((void*)k_lstm, dim3(256), dim3(256), args, 0, stream);
    }

    // 8. adapter 1 + LN -> d_out x (f32)
    k_adp1<<<256, 64, 0, stream>>>(p_y, p_params + 262144, p_t0);
    k_adp2<<<dim3(64, 16), 256, 0, stream>>>(p_t0, p_params + 262144 + 131072, p_z);
    k_ln<0><<<4096, 256, 0, stream>>>(p_z, lng1, lnb1, (void*)outx);
}

// Round 2
// 13327.864 us; speedup vs baseline: 2.6071x; 2.6071x over previous
//
#include <hip/hip_runtime.h>

using u16 = unsigned short;
using u32 = unsigned int;
typedef __attribute__((ext_vector_type(8))) __bf16 bf16x8;
typedef __attribute__((ext_vector_type(8))) short s16x8;
typedef __attribute__((ext_vector_type(4))) float f32x4;

static_assert(sizeof(bf16x8) == 16, "bf16x8 must be 16B");

// ---------- helpers ----------
__device__ __forceinline__ u16 f2bf(float f) {
    unsigned int u = __float_as_uint(f);
    u = (u + 0x7FFFu + ((u >> 16) & 1u)) >> 16;
    return (u16)u;
}
__device__ __forceinline__ float bf2f(u16 v) {
    return __uint_as_float(((unsigned int)v) << 16);
}
__device__ __forceinline__ bf16x8 load8(const u16* p) {
    s16x8 v = *reinterpret_cast<const s16x8*>(p);
    return __builtin_bit_cast(bf16x8, v);
}
__device__ __forceinline__ f32x4 mfma16(bf16x8 a, bf16x8 b, f32x4 c) {
    return __builtin_amdgcn_mfma_f32_16x16x32_bf16(a, b, c, 0, 0, 0);
}
__device__ __forceinline__ void gl_lds16(const void* g, void* s) {
    __builtin_amdgcn_global_load_lds((const __attribute__((address_space(1))) void*)g,
                                     (__attribute__((address_space(3))) void*)s, 16, 0, 0);
}
__device__ __forceinline__ float sigm(float x) { return 1.f / (1.f + __expf(-x)); }
__device__ __forceinline__ float tanh_(float x) {
    const float a = __expf(-2.f * fabsf(x));
    const float t = (1.f - a) / (1.f + a);
    return x >= 0.f ? t : -t;
}

// ---------- sizes ----------
#define T_SEQ 512

// ws byte offsets
#define O_PARAMS 0ull
#define O_XBF    1048576ull
#define O_SYNC   1048576ull    // overlays xbf (dead after layer-0 input GEMMs)
#define O_WIH0F  9437184ull
#define O_WIH0R  17825792ull
#define O_WIH1F  26214400ull
#define O_WIH1R  42991616ull
#define O_WHH0F  59768832ull
#define O_WHH0R  68157440ull
#define O_WHH1F  76546048ull
#define O_WHH1R  84934656ull
#define O_XG     93323264ull   // [2][512][8][4096] bf16  (z overlays this later)
#define O_Y      160432128ull  // [8][512][2048] bf16
#define O_X1     177209344ull  // [4096][2048] bf16
#define O_T0     193986560ull  // [4096][64] bf16
#define O_HBUF   194510848ull  // [2][2][16][1024] bf16
#define O_H0S    194641920ull  // [2][8][1024] f32
#define O_C0S    194707456ull  // [2][8][1024] f32

// ---------- hand-rolled per-direction barrier (one-hop, all-poll-all) ----------
// flags: 128 u32, one per WG of this direction. target is monotonically
// increasing per barrier instance, so no reset between instances is needed.
__device__ __forceinline__ void dir_barrier(u32* flags, u32 target, int wgl) {
    __syncthreads();   // all waves' prior stores issued & waited (vmcnt) per-wave
    if (threadIdx.x < 64) {
        if (threadIdx.x == 0)
            __hip_atomic_store(&flags[wgl], target, __ATOMIC_RELEASE, __HIP_MEMORY_SCOPE_AGENT);
        u32 a, b;
        do {
            a = __hip_atomic_load(&flags[threadIdx.x], __ATOMIC_RELAXED, __HIP_MEMORY_SCOPE_AGENT);
            b = __hip_atomic_load(&flags[threadIdx.x + 64], __ATOMIC_RELAXED, __HIP_MEMORY_SCOPE_AGENT);
        } while (!__all(a >= target && b >= target));
        __builtin_amdgcn_fence(__ATOMIC_ACQUIRE, "agent");
    }
    __syncthreads();
}

// ---------- hypernetwork matvec + slice to bf16 ----------
__global__ void k_params(const float* __restrict__ hw, const float* __restrict__ emb,
                         const int* __restrict__ lid, u16* __restrict__ pout) {
    const int i = blockIdx.x * 256 + threadIdx.x;   // < 524288
    const float* e = emb + lid[0] * 32;
    const float* w = hw + (size_t)i * 32;
    float s = 0.f;
#pragma unroll
    for (int k = 0; k < 32; ++k) s += w[k] * e[k];
    pout[i] = f2bf(s);
}

// ---------- f32 -> bf16 conversion (float4-wide) ----------
__global__ void k_cvt(const float* __restrict__ in, u16* __restrict__ out, int n4) {
    const int i = blockIdx.x * 256 + threadIdx.x;
    if (i >= n4) return;
    const float4 v = ((const float4*)in)[i];
    ushort4 o;
    o.x = f2bf(v.x); o.y = f2bf(v.y); o.z = f2bf(v.z); o.w = f2bf(v.w);
    ((ushort4*)out)[i] = o;
}

// ---------- input-projection GEMM: Xg[t][b][n] = A[m]·Bw[n] + bih[n]+bhh[n] ----------
template <int K>
__global__ __launch_bounds__(256, 2)
void k_gemm_xg(const u16* __restrict__ A, const u16* __restrict__ Bw,
               const float* __restrict__ bih, const float* __restrict__ bhh,
               u16* __restrict__ Xg) {
    __shared__ __align__(16) u16 Al[128 * 32];
    __shared__ __align__(16) u16 Bl[128 * 32];
    const int tid = threadIdx.x;
    const int wv = tid >> 6, l = tid & 63;
    const int m0 = blockIdx.x * 128, n0 = blockIdx.y * 128;
    const int wr = (wv >> 1) * 64, wc = (wv & 1) * 64;
    const int r8 = l >> 2;          // 0..15
    const int c8 = (l & 3) * 8;     // 0,8,16,24
    f32x4 acc[4][4] = {};

    for (int k0 = 0; k0 < K; k0 += 32) {
#pragma unroll
        for (int q = 0; q < 2; ++q) {
            const int inst = wv * 2 + q;
            const int row = inst * 16 + r8;
            gl_lds16(A + (size_t)(m0 + row) * K + k0 + c8, (void*)(Al + inst * 512));
            gl_lds16(Bw + (size_t)(n0 + row) * K + k0 + c8, (void*)(Bl + inst * 512));
        }
        __syncthreads();
        bf16x8 af[4], bfv[4];
#pragma unroll
        for (int i = 0; i < 4; ++i) {
            af[i]  = load8(&Al[(wr + i * 16 + (l & 15)) * 32 + ((l >> 4) * 8)]);
            bfv[i] = load8(&Bl[(wc + i * 16 + (l & 15)) * 32 + ((l >> 4) * 8)]);
        }
#pragma unroll
        for (int i = 0; i < 4; ++i)
#pragma unroll
            for (int j = 0; j < 4; ++j)
                acc[i][j] = mfma16(af[i], bfv[j], acc[i][j]);
        __syncthreads();
    }
    const int b = m0 >> 9;   // uniform per block
#pragma unroll
    for (int i = 0; i < 4; ++i)
#pragma unroll
        for (int j = 0; j < 4; ++j)
#pragma unroll
            for (int r = 0; r < 4; ++r) {
                const int m = m0 + wr + i * 16 + (l >> 4) * 4 + r;
                const int n = n0 + wc + j * 16 + (l & 15);
                const int t = m & 511;
                const float v = acc[i][j][r] + bih[n] + bhh[n];
                Xg[((size_t)(t * 8 + b)) * 4096 + n] = f2bf(v);
            }
}

// ---------- persistent bi-LSTM recurrence (cooperative launch for co-residency) ----------
// 256 WGs: WGs [0,128) forward, [128,256) reverse. Each WG owns 8 h-columns.
__global__ __launch_bounds__(256, 1)
void k_lstm(const u16* __restrict__ Xg,     // [2][512][8][4096] bf16
            const u16* __restrict__ WhhF, const u16* __restrict__ WhhR,  // 4096x1024 bf16
            const float* __restrict__ h0, const float* __restrict__ c0,  // [2][8][1024]
            int has_init,
            u16* __restrict__ hbuf,         // [2][2][16][1024] bf16 (dbuf)
            u16* __restrict__ y,            // [8][512][2048] bf16
            float* __restrict__ hfin, float* __restrict__ cfin,          // [2][8][1024]
            u32* __restrict__ syncbase) {   // [2][128] u32, pre-zeroed
    const int wg = blockIdx.x;
    const int dir = wg >> 7;
    const int wgl = wg & 127;
    u32* flags = syncbase + dir * 128;
    const int j0 = wgl * 8;
    const int tid = threadIdx.x;
    const int wv = tid >> 6, l = tid & 63;
    const int kh = wv >> 1, nt = wv & 1;
    __shared__ __align__(16) float gpart[4][16][16];   // [wave][gate-col][batch-row]

    const u16* Whh = dir ? WhhR : WhhF;
    // persistent B-fragments: this wave's 16 gate columns x its K-half, in VGPRs
    bf16x8 bfr[16];
    {
        const int idx = nt * 16 + (l & 15);
        const size_t rowb = (size_t)((idx >> 3) * 1024 + j0 + (idx & 7)) * 1024;
        const int kb = kh * 512 + ((l >> 4) * 8);
#pragma unroll
        for (int m = 0; m < 16; ++m) bfr[m] = load8(Whh + rowb + kb + m * 32);
    }
    const int jj = l & 7, bb = l >> 3;
    float c_r = 0.f;
    if (wv == 0) {
        float hinit = 0.f;
        if (has_init) {
            c_r   = c0[dir * 8192 + bb * 1024 + j0 + jj];
            hinit = h0[dir * 8192 + bb * 1024 + j0 + jj];
        }
        hbuf[dir * 32768 + bb * 1024 + j0 + jj] = f2bf(hinit);
    }
    dir_barrier(flags, 1u, wgl);

    const size_t xg_dir = (size_t)dir * T_SEQ * 8 * 4096;
    for (int t = 0; t < T_SEQ; ++t) {
        const int rd = t & 1;
        const int tt = dir ? (T_SEQ - 1 - t) : t;
        // A-fragments: full h from the read buffer (rows 8..15 are pad, harmless)
        const u16* hb = hbuf + dir * 32768 + rd * 16384 + (size_t)(l & 15) * 1024 + kh * 512 + ((l >> 4) * 8);
        bf16x8 afr[16];
#pragma unroll
        for (int m = 0; m < 16; ++m) afr[m] = load8(hb + m * 32);
        f32x4 acc = {0.f, 0.f, 0.f, 0.f};
#pragma unroll
        for (int m = 0; m < 16; ++m) acc = mfma16(afr[m], bfr[m], acc);
        *reinterpret_cast<f32x4*>(&gpart[wv][l & 15][(l >> 4) * 4]) = acc;
        __syncthreads();
        if (wv == 0) {
            const u16* xr = Xg + xg_dir + ((size_t)tt * 8 + bb) * 4096 + j0 + jj;
            const float gi = gpart[0][jj][bb]     + gpart[2][jj][bb]     + bf2f(xr[0]);
            const float gf = gpart[0][8 + jj][bb] + gpart[2][8 + jj][bb] + bf2f(xr[1024]);
            const float gg = gpart[1][jj][bb]     + gpart[3][jj][bb]     + bf2f(xr[2048]);
            const float go = gpart[1][8 + jj][bb] + gpart[3][8 + jj][bb] + bf2f(xr[3072]);
            const float i_ = sigm(gi), f_ = sigm(gf), g_ = tanh_(gg), o_ = sigm(go);
            c_r = f_ * c_r + i_ * g_;
            const float h_ = o_ * tanh_(c_r);
            const u16 h16 = f2bf(h_);
            hbuf[dir * 32768 + (rd ^ 1) * 16384 + bb * 1024 + j0 + jj] = h16;
            y[(size_t)bb * (T_SEQ * 2048) + (size_t)tt * 2048 + dir * 1024 + j0 + jj] = h16;
            if (t == T_SEQ - 1) {
                hfin[dir * 8192 + bb * 1024 + j0 + jj] = h_;
                cfin[dir * 8192 + bb * 1024 + j0 + jj] = c_r;
            }
        }
        dir_barrier(flags, (u32)(t + 2), wgl);
    }
}

// ---------- adapter GEMM1: t0 = relu(y @ w_down^T), (4096 x 64), K=2048 ----------
__global__ __launch_bounds__(64, 1)
void k_adp1(const u16* __restrict__ y, const u16* __restrict__ wd, u16* __restrict__ t0) {
    const int l = threadIdx.x;
    const int m0 = blockIdx.x * 16;
    const int ko = (l >> 4) * 8;
    f32x4 acc[4] = {};
    for (int k = 0; k < 2048; k += 32) {
        const bf16x8 a = load8(y + (size_t)(m0 + (l & 15)) * 2048 + k + ko);
#pragma unroll
        for (int ni = 0; ni < 4; ++ni) {
            const bf16x8 b = load8(wd + (size_t)(ni * 16 + (l & 15)) * 2048 + k + ko);
            acc[ni] = mfma16(a, b, acc[ni]);
        }
    }
#pragma unroll
    for (int ni = 0; ni < 4; ++ni)
#pragma unroll
        for (int r = 0; r < 4; ++r) {
            const int m = m0 + (l >> 4) * 4 + r;
            const int n = ni * 16 + (l & 15);
            t0[(size_t)m * 64 + n] = f2bf(fmaxf(acc[ni][r], 0.f));
        }
}

// ---------- adapter GEMM2: z = t0 @ w_up^T, (4096 x 2048), K=64 ----------
__global__ __launch_bounds__(256, 2)
void k_adp2(const u16* __restrict__ t0, const u16* __restrict__ wu, float* __restrict__ z) {
    const int tid = threadIdx.x, wv = tid >> 6, l = tid & 63;
    const int m0 = blockIdx.x * 64 + wv * 16;
    const int n0 = blockIdx.y * 128;
    const int ko = (l >> 4) * 8;
    const bf16x8 a0 = load8(t0 + (size_t)(m0 + (l & 15)) * 64 + ko);
    const bf16x8 a1 = load8(t0 + (size_t)(m0 + (l & 15)) * 64 + 32 + ko);
#pragma unroll
    for (int ni = 0; ni < 8; ++ni) {
        const int n = n0 + ni * 16;
        const bf16x8 b0 = load8(wu + (size_t)(n + (l & 15)) * 64 + ko);
        const bf16x8 b1 = load8(wu + (size_t)(n + (l & 15)) * 64 + 32 + ko);
        f32x4 c = {0.f, 0.f, 0.f, 0.f};
        c = mfma16(a0, b0, c);
        c = mfma16(a1, b1, c);
#pragma unroll
        for (int r = 0; r < 4; ++r)
            z[(size_t)(m0 + (l >> 4) * 4 + r) * 2048 + n + (l & 15)] = c[r];
    }
}

// ---------- LayerNorm over 2048, optional bf16 output ----------
template <int BF16OUT>
__global__ __launch_bounds__(256, 4)
void k_ln(const float* __restrict__ z, const float* __restrict__ g,
          const float* __restrict__ be, void* __restrict__ out) {
    const int row = blockIdx.x, tid = threadIdx.x;
    const float* zr = z + (size_t)row * 2048;
    const float4 v0 = ((const float4*)zr)[tid * 2];
    const float4 v1 = ((const float4*)zr)[tid * 2 + 1];
    float o[8] = {v0.x, v0.y, v0.z, v0.w, v1.x, v1.y, v1.z, v1.w};
    float s = 0.f, q = 0.f;
#pragma unroll
    for (int i = 0; i < 8; ++i) { s += o[i]; q += o[i] * o[i]; }
#pragma unroll
    for (int off = 32; off > 0; off >>= 1) { s += __shfl_xor(s, off); q += __shfl_xor(q, off); }
    __shared__ float sm[8];
    const int wv = tid >> 6;
    if ((tid & 63) == 0) { sm[wv] = s; sm[4 + wv] = q; }
    __syncthreads();
    const float stot = sm[0] + sm[1] + sm[2] + sm[3];
    const float qtot = sm[4] + sm[5] + sm[6] + sm[7];
    const float mean = stot * (1.f / 2048.f);
    const float var = qtot * (1.f / 2048.f) - mean * mean;
    const float rs = rsqrtf(var + 1e-5f);
    const int c = tid * 8;
#pragma unroll
    for (int i = 0; i < 8; ++i) o[i] = (o[i] - mean) * rs * g[c + i] + be[c + i];
    if (BF16OUT) {
        u16* ob = (u16*)out + (size_t)row * 2048 + c;
#pragma unroll
        for (int i = 0; i < 8; ++i) ob[i] = f2bf(o[i]);
    } else {
        float* of = (float*)out + (size_t)row * 2048 + c;
        ((float4*)of)[0] = make_float4(o[0], o[1], o[2], o[3]);
        ((float4*)of)[1] = make_float4(o[4], o[5], o[6], o[7]);
    }
}

// ---------- host ----------
static inline void cvt_launch(const float* src, u16* dst, int n, hipStream_t s) {
    const int n4 = n / 4;
    k_cvt<<<(n4 + 255) / 256, 256, 0, s>>>(src, dst, n4);
}

extern "C" void kernel_launch(void* const* d_in, const int* in_sizes, int n_in,
                              void* d_out, int out_size, void* d_ws, size_t ws_size,
                              hipStream_t stream) {
    const float* x     = (const float*)d_in[0];
    const float* lemb  = (const float*)d_in[1];
    const float* hw    = (const float*)d_in[2];
    const float* wih0f = (const float*)d_in[3];
    const float* whh0f = (const float*)d_in[4];
    const float* bih0f = (const float*)d_in[5];
    const float* bhh0f = (const float*)d_in[6];
    const float* wih0r = (const float*)d_in[7];
    const float* whh0r = (const float*)d_in[8];
    const float* bih0r = (const float*)d_in[9];
    const float* bhh0r = (const float*)d_in[10];
    const float* lng0  = (const float*)d_in[11];
    const float* lnb0  = (const float*)d_in[12];
    const float* wih1f = (const float*)d_in[13];
    const float* whh1f = (const float*)d_in[14];
    const float* bih1f = (const float*)d_in[15];
    const float* bhh1f = (const float*)d_in[16];
    const float* wih1r = (const float*)d_in[17];
    const float* whh1r = (const float*)d_in[18];
    const float* bih1r = (const float*)d_in[19];
    const float* bhh1r = (const float*)d_in[20];
    const float* lng1  = (const float*)d_in[21];
    const float* lnb1  = (const float*)d_in[22];
    const int*   lid   = (const int*)d_in[23];

    char* ws = (char*)d_ws;
    u16* p_params = (u16*)(ws + O_PARAMS);
    u16* p_xbf    = (u16*)(ws + O_XBF);
    u16* p_wih0f  = (u16*)(ws + O_WIH0F);
    u16* p_wih0r  = (u16*)(ws + O_WIH0R);
    u16* p_wih1f  = (u16*)(ws + O_WIH1F);
    u16* p_wih1r  = (u16*)(ws + O_WIH1R);
    u16* p_whh0f  = (u16*)(ws + O_WHH0F);
    u16* p_whh0r  = (u16*)(ws + O_WHH0R);
    u16* p_whh1f  = (u16*)(ws + O_WHH1F);
    u16* p_whh1r  = (u16*)(ws + O_WHH1R);
    u16* p_xg     = (u16*)(ws + O_XG);
    u16* p_y      = (u16*)(ws + O_Y);
    u16* p_x1     = (u16*)(ws + O_X1);
    u16* p_t0     = (u16*)(ws + O_T0);
    u16* p_hbuf   = (u16*)(ws + O_HBUF);
    float* p_h0s  = (float*)(ws + O_H0S);
    float* p_c0s  = (float*)(ws + O_C0S);
    float* p_z    = (float*)(ws + O_XG);   // overlays Xg (dead when z is live)
    u32* p_sync0  = (u32*)(ws + O_SYNC);         // [2][128] u32
    u32* p_sync1  = (u32*)(ws + O_SYNC + 1024);  // [2][128] u32

    float* outx = (float*)d_out;
    float* outh = outx + 8 * 512 * 2048;
    float* outc = outh + 2 * 8 * 1024;

    // 1. hypernetwork params -> bf16 adapters
    k_params<<<2048, 256, 0, stream>>>(hw, lemb, lid, p_params);
    // 2. conversions to bf16
    cvt_launch(x, p_xbf, 4194304, stream);
    cvt_launch(wih0f, p_wih0f, 4194304, stream);
    cvt_launch(wih0r, p_wih0r, 4194304, stream);
    cvt_launch(wih1f, p_wih1f, 8388608, stream);
    cvt_launch(wih1r, p_wih1r, 8388608, stream);
    cvt_launch(whh0f, p_whh0f, 4194304, stream);
    cvt_launch(whh0r, p_whh0r, 4194304, stream);
    cvt_launch(whh1f, p_whh1f, 4194304, stream);
    cvt_launch(whh1r, p_whh1r, 4194304, stream);

    // 3. layer 0 input projections (f and r)
    k_gemm_xg<1024><<<dim3(32, 32), 256, 0, stream>>>(p_xbf, p_wih0f, bih0f, bhh0f, p_xg);
    k_gemm_xg<1024><<<dim3(32, 32), 256, 0, stream>>>(p_xbf, p_wih0r, bih0r, bhh0r, p_xg + 16777216);

    // 3b. zero barrier flags (xbf region is dead from here on; ws is 0xAA-poisoned
    //     each call, so this memset is mandatory every launch)
    hipMemsetAsync((void*)(ws + O_SYNC), 0, 2048, stream);

    // 4. layer 0 recurrence (cooperative launch for guaranteed co-residency)
    {
        const u16* xg_c = p_xg; const u16* wf = p_whh0f; const u16* wr = p_whh0r;
        const float* h0p = p_h0s; const float* c0p = p_c0s; int has = 0;
        u16* hb = p_hbuf; u16* yy = p_y; float* hf = p_h0s; float* cf = p_c0s;
        u32* sy = p_sync0;
        void* args[] = {&xg_c, &wf, &wr, &h0p, &c0p, &has, &hb, &yy, &hf, &cf, &sy};
        hipLaunchCooperativeKernel((void*)k_lstm, dim3(256), dim3(256), args, 0, stream);
    }

    // 5. adapter 0 + LN -> x1 (bf16)
    k_adp1<<<256, 64, 0, stream>>>(p_y, p_params, p_t0);
    k_adp2<<<dim3(64, 16), 256, 0, stream>>>(p_t0, p_params + 131072, p_z);
    k_ln<1><<<4096, 256, 0, stream>>>(p_z, lng0, lnb0, (void*)p_x1);

    // 6. layer 1 input projections
    k_gemm_xg<2048><<<dim3(32, 32), 256, 0, stream>>>(p_x1, p_wih1f, bih1f, bhh1f, p_xg);
    k_gemm_xg<2048><<<dim3(32, 32), 256, 0, stream>>>(p_x1, p_wih1r, bih1r, bhh1r, p_xg + 16777216);

    // 7. layer 1 recurrence (initial state = layer 0 finals), finals -> d_out
    {
        const u16* xg_c = p_xg; const u16* wf = p_whh1f; const u16* wr = p_whh1r;
        const float* h0p = p_h0s; const float* c0p = p_c0s; int has = 1;
        u16* hb = p_hbuf; u16* yy = p_y; float* hf = outh; float* cf = outc;
        u32* sy = p_sync1;
        void* args[] = {&xg_c, &wf, &wr, &h0p, &c0p, &has, &hb, &yy, &hf, &cf, &sy};
        hipLaunchCooperativeKernel((void*)k_lstm, dim3(256), dim3(256), args, 0, stream);
    }

    // 8. adapter 1 + LN -> d_out x (f32)
    k_adp1<<<256, 64, 0, stream>>>(p_y, p_params + 262144, p_t0);
    k_adp2<<<dim3(64, 16), 256, 0, stream>>>(p_t0, p_params + 262144 + 131072, p_z);
    k_ln<0><<<4096, 256, 0, stream>>>(p_z, lng1, lnb1, (void*)outx);
}

// Round 3
// 11016.644 us; speedup vs baseline: 3.1541x; 1.2098x over previous
//
#include <hip/hip_runtime.h>

using u16 = unsigned short;
using u32 = unsigned int;
using u64 = unsigned long long;
typedef __attribute__((ext_vector_type(8))) __bf16 bf16x8;
typedef __attribute__((ext_vector_type(8))) short s16x8;
typedef __attribute__((ext_vector_type(4))) float f32x4;
typedef __attribute__((ext_vector_type(2))) u64 u64x2;

static_assert(sizeof(bf16x8) == 16, "bf16x8 must be 16B");

// ---------- helpers ----------
__device__ __forceinline__ u16 f2bf(float f) {
    unsigned int u = __float_as_uint(f);
    u = (u + 0x7FFFu + ((u >> 16) & 1u)) >> 16;
    return (u16)u;
}
__device__ __forceinline__ float bf2f(u16 v) {
    return __uint_as_float(((unsigned int)v) << 16);
}
__device__ __forceinline__ bf16x8 load8(const u16* p) {
    s16x8 v = *reinterpret_cast<const s16x8*>(p);
    return __builtin_bit_cast(bf16x8, v);
}
// agent-scope (sc0 sc1) 16B load as two u64 atomics: bypasses local L2 so
// remote write-through stores are visible WITHOUT any buffer_inv.
__device__ __forceinline__ bf16x8 load8_agent(const u16* p) {
    const u64* q = (const u64*)p;
    u64 v0 = __hip_atomic_load(q,     __ATOMIC_RELAXED, __HIP_MEMORY_SCOPE_AGENT);
    u64 v1 = __hip_atomic_load(q + 1, __ATOMIC_RELAXED, __HIP_MEMORY_SCOPE_AGENT);
    u64x2 t = {v0, v1};
    return __builtin_bit_cast(bf16x8, t);
}
__device__ __forceinline__ f32x4 mfma16(bf16x8 a, bf16x8 b, f32x4 c) {
    return __builtin_amdgcn_mfma_f32_16x16x32_bf16(a, b, c, 0, 0, 0);
}
__device__ __forceinline__ void gl_lds16(const void* g, void* s) {
    __builtin_amdgcn_global_load_lds((const __attribute__((address_space(1))) void*)g,
                                     (__attribute__((address_space(3))) void*)s, 16, 0, 0);
}
__device__ __forceinline__ float sigm(float x) { return 1.f / (1.f + __expf(-x)); }
__device__ __forceinline__ float tanh_(float x) {
    const float a = __expf(-2.f * fabsf(x));
    const float t = (1.f - a) / (1.f + a);
    return x >= 0.f ? t : -t;
}

// ---------- sizes ----------
#define T_SEQ 512

// ws byte offsets
#define O_PARAMS 0ull
#define O_XBF    1048576ull
#define O_SYNC   1048576ull    // overlays xbf (dead after layer-0 input GEMMs)
#define O_WIH0F  9437184ull
#define O_WIH0R  17825792ull
#define O_WIH1F  26214400ull
#define O_WIH1R  42991616ull
#define O_WHH0F  59768832ull
#define O_WHH0R  68157440ull
#define O_WHH1F  76546048ull
#define O_WHH1R  84934656ull
#define O_XG     93323264ull   // [2][512][8][4096] bf16  (z overlays this later)
#define O_Y      160432128ull  // [8][512][2048] bf16
#define O_X1     177209344ull  // [4096][2048] bf16
#define O_T0     193986560ull  // [4096][64] bf16
#define O_HBUF   194510848ull  // [2][2][16][1024] bf16 (dbuf)
#define O_H0S    194641920ull  // [2][8][1024] f32
#define O_C0S    194707456ull  // [2][8][1024] f32

// ---------- fence-free per-direction barrier ----------
// Producer data (h) was stored write-through (agent atomics), so arrival needs
// only vmcnt(0) (acks past coherence point) + a relaxed write-through flag.
// Detection needs only relaxed agent polls. NO buffer_wbl2 / buffer_inv.
__device__ __forceinline__ void dir_barrier(u32* flags, u32 target, int wgl) {
    __syncthreads();
    if (threadIdx.x < 64) {
        if (threadIdx.x == 0) {
            asm volatile("s_waitcnt vmcnt(0)" ::: "memory");
            __hip_atomic_store(&flags[wgl], target, __ATOMIC_RELAXED, __HIP_MEMORY_SCOPE_AGENT);
        }
        u32 a, b;
        do {
            a = __hip_atomic_load(&flags[threadIdx.x], __ATOMIC_RELAXED, __HIP_MEMORY_SCOPE_AGENT);
            b = __hip_atomic_load(&flags[threadIdx.x + 64], __ATOMIC_RELAXED, __HIP_MEMORY_SCOPE_AGENT);
        } while (!__all(a >= target && b >= target));
    }
    __syncthreads();
}

// ---------- hypernetwork matvec + slice to bf16 ----------
__global__ void k_params(const float* __restrict__ hw, const float* __restrict__ emb,
                         const int* __restrict__ lid, u16* __restrict__ pout) {
    const int i = blockIdx.x * 256 + threadIdx.x;   // < 524288
    const float* e = emb + lid[0] * 32;
    const float* w = hw + (size_t)i * 32;
    float s = 0.f;
#pragma unroll
    for (int k = 0; k < 32; ++k) s += w[k] * e[k];
    pout[i] = f2bf(s);
}

// ---------- f32 -> bf16 conversion (float4-wide) ----------
__global__ void k_cvt(const float* __restrict__ in, u16* __restrict__ out, int n4) {
    const int i = blockIdx.x * 256 + threadIdx.x;
    if (i >= n4) return;
    const float4 v = ((const float4*)in)[i];
    ushort4 o;
    o.x = f2bf(v.x); o.y = f2bf(v.y); o.z = f2bf(v.z); o.w = f2bf(v.w);
    ((ushort4*)out)[i] = o;
}

// ---------- input-projection GEMM: Xg[t][b][n] = A[m]·Bw[n] + bih[n]+bhh[n] ----------
template <int K>
__global__ __launch_bounds__(256, 2)
void k_gemm_xg(const u16* __restrict__ A, const u16* __restrict__ Bw,
               const float* __restrict__ bih, const float* __restrict__ bhh,
               u16* __restrict__ Xg) {
    __shared__ __align__(16) u16 Al[128 * 32];
    __shared__ __align__(16) u16 Bl[128 * 32];
    const int tid = threadIdx.x;
    const int wv = tid >> 6, l = tid & 63;
    const int m0 = blockIdx.x * 128, n0 = blockIdx.y * 128;
    const int wr = (wv >> 1) * 64, wc = (wv & 1) * 64;
    const int r8 = l >> 2;          // 0..15
    const int c8 = (l & 3) * 8;     // 0,8,16,24
    f32x4 acc[4][4] = {};

    for (int k0 = 0; k0 < K; k0 += 32) {
#pragma unroll
        for (int q = 0; q < 2; ++q) {
            const int inst = wv * 2 + q;
            const int row = inst * 16 + r8;
            gl_lds16(A + (size_t)(m0 + row) * K + k0 + c8, (void*)(Al + inst * 512));
            gl_lds16(Bw + (size_t)(n0 + row) * K + k0 + c8, (void*)(Bl + inst * 512));
        }
        __syncthreads();
        bf16x8 af[4], bfv[4];
#pragma unroll
        for (int i = 0; i < 4; ++i) {
            af[i]  = load8(&Al[(wr + i * 16 + (l & 15)) * 32 + ((l >> 4) * 8)]);
            bfv[i] = load8(&Bl[(wc + i * 16 + (l & 15)) * 32 + ((l >> 4) * 8)]);
        }
#pragma unroll
        for (int i = 0; i < 4; ++i)
#pragma unroll
            for (int j = 0; j < 4; ++j)
                acc[i][j] = mfma16(af[i], bfv[j], acc[i][j]);
        __syncthreads();
    }
    const int b = m0 >> 9;   // uniform per block
#pragma unroll
    for (int i = 0; i < 4; ++i)
#pragma unroll
        for (int j = 0; j < 4; ++j)
#pragma unroll
            for (int r = 0; r < 4; ++r) {
                const int m = m0 + wr + i * 16 + (l >> 4) * 4 + r;
                const int n = n0 + wc + j * 16 + (l & 15);
                const int t = m & 511;
                const float v = acc[i][j][r] + bih[n] + bhh[n];
                Xg[((size_t)(t * 8 + b)) * 4096 + n] = f2bf(v);
            }
}

// ---------- persistent bi-LSTM recurrence (cooperative launch for co-residency) ----------
// 256 WGs: WGs [0,128) forward, [128,256) reverse. Each WG owns 8 h-columns.
__global__ __launch_bounds__(256, 1)
void k_lstm(const u16* __restrict__ Xg,     // [2][512][8][4096] bf16
            const u16* __restrict__ WhhF, const u16* __restrict__ WhhR,  // 4096x1024 bf16
            const float* __restrict__ h0, const float* __restrict__ c0,  // [2][8][1024]
            int has_init,
            u16* __restrict__ hbuf,         // [2][2][16][1024] bf16 (dbuf)
            u16* __restrict__ y,            // [8][512][2048] bf16
            float* __restrict__ hfin, float* __restrict__ cfin,          // [2][8][1024]
            u32* __restrict__ syncbase) {   // [2][128] u32, pre-zeroed
    const int wg = blockIdx.x;
    const int dir = wg >> 7;
    const int wgl = wg & 127;
    u32* flags = syncbase + dir * 128;
    const int j0 = wgl * 8;
    const int tid = threadIdx.x;
    const int wv = tid >> 6, l = tid & 63;
    const int kh = wv >> 1, nt = wv & 1;
    __shared__ __align__(16) float gpart[4][16][16];   // [wave][gate-col][batch-row]

    const u16* Whh = dir ? WhhR : WhhF;
    // persistent B-fragments: this wave's 16 gate columns x its K-half, in VGPRs
    bf16x8 bfr[16];
    {
        const int idx = nt * 16 + (l & 15);
        const size_t rowb = (size_t)((idx >> 3) * 1024 + j0 + (idx & 7)) * 1024;
        const int kb = kh * 512 + ((l >> 4) * 8);
#pragma unroll
        for (int m = 0; m < 16; ++m) bfr[m] = load8(Whh + rowb + kb + m * 32);
    }
    const int jj = l & 7, bb = l >> 3;
    float c_r = 0.f;
    if (wv == 0) {
        float hinit = 0.f;
        if (has_init) {
            c_r   = c0[dir * 8192 + bb * 1024 + j0 + jj];
            hinit = h0[dir * 8192 + bb * 1024 + j0 + jj];
        }
        // packed write-through store of the initial h (pairs from even lanes)
        const u16 h16 = f2bf(hinit);
        const int partner = __shfl_down((int)h16, 1);
        if ((l & 1) == 0) {
            const u32 pv = (u32)h16 | ((u32)partner << 16);
            u32* dst = (u32*)(hbuf + dir * 32768 + bb * 1024 + j0 + jj);
            __hip_atomic_store(dst, pv, __ATOMIC_RELAXED, __HIP_MEMORY_SCOPE_AGENT);
        }
    }
    dir_barrier(flags, 1u, wgl);

    const size_t xg_dir = (size_t)dir * T_SEQ * 8 * 4096;
    for (int t = 0; t < T_SEQ; ++t) {
        const int rd = t & 1;
        const int tt = dir ? (T_SEQ - 1 - t) : t;
        // A-fragments: full h via agent-scope loads (rows 8..15 are pad, harmless)
        const u16* hb = hbuf + dir * 32768 + rd * 16384 + (size_t)(l & 15) * 1024 + kh * 512 + ((l >> 4) * 8);
        bf16x8 afr[16];
#pragma unroll
        for (int m = 0; m < 16; ++m) afr[m] = load8_agent(hb + m * 32);
        f32x4 acc = {0.f, 0.f, 0.f, 0.f};
#pragma unroll
        for (int m = 0; m < 16; ++m) acc = mfma16(afr[m], bfr[m], acc);
        *reinterpret_cast<f32x4*>(&gpart[wv][l & 15][(l >> 4) * 4]) = acc;
        __syncthreads();
        if (wv == 0) {
            const u16* xr = Xg + xg_dir + ((size_t)tt * 8 + bb) * 4096 + j0 + jj;
            const float gi = gpart[0][jj][bb]     + gpart[2][jj][bb]     + bf2f(xr[0]);
            const float gf = gpart[0][8 + jj][bb] + gpart[2][8 + jj][bb] + bf2f(xr[1024]);
            const float gg = gpart[1][jj][bb]     + gpart[3][jj][bb]     + bf2f(xr[2048]);
            const float go = gpart[1][8 + jj][bb] + gpart[3][8 + jj][bb] + bf2f(xr[3072]);
            const float i_ = sigm(gi), f_ = sigm(gf), g_ = tanh_(gg), o_ = sigm(go);
            c_r = f_ * c_r + i_ * g_;
            const float h_ = o_ * tanh_(c_r);
            const u16 h16 = f2bf(h_);
            // write-through packed h store (cross-WG data)
            const int partner = __shfl_down((int)h16, 1);
            if ((l & 1) == 0) {
                const u32 pv = (u32)h16 | ((u32)partner << 16);
                u32* dst = (u32*)(hbuf + dir * 32768 + (rd ^ 1) * 16384 + bb * 1024 + j0 + jj);
                __hip_atomic_store(dst, pv, __ATOMIC_RELAXED, __HIP_MEMORY_SCOPE_AGENT);
            }
            // y / finals: normal cached stores (consumed only after kernel end)
            y[(size_t)bb * (T_SEQ * 2048) + (size_t)tt * 2048 + dir * 1024 + j0 + jj] = h16;
            if (t == T_SEQ - 1) {
                hfin[dir * 8192 + bb * 1024 + j0 + jj] = h_;
                cfin[dir * 8192 + bb * 1024 + j0 + jj] = c_r;
            }
        }
        dir_barrier(flags, (u32)(t + 2), wgl);
    }
}

// ---------- adapter GEMM1: t0 = relu(y @ w_down^T), (4096 x 64), K=2048 ----------
__global__ __launch_bounds__(64, 1)
void k_adp1(const u16* __restrict__ y, const u16* __restrict__ wd, u16* __restrict__ t0) {
    const int l = threadIdx.x;
    const int m0 = blockIdx.x * 16;
    const int ko = (l >> 4) * 8;
    f32x4 acc[4] = {};
    for (int k = 0; k < 2048; k += 32) {
        const bf16x8 a = load8(y + (size_t)(m0 + (l & 15)) * 2048 + k + ko);
#pragma unroll
        for (int ni = 0; ni < 4; ++ni) {
            const bf16x8 b = load8(wd + (size_t)(ni * 16 + (l & 15)) * 2048 + k + ko);
            acc[ni] = mfma16(a, b, acc[ni]);
        }
    }
#pragma unroll
    for (int ni = 0; ni < 4; ++ni)
#pragma unroll
        for (int r = 0; r < 4; ++r) {
            const int m = m0 + (l >> 4) * 4 + r;
            const int n = ni * 16 + (l & 15);
            t0[(size_t)m * 64 + n] = f2bf(fmaxf(acc[ni][r], 0.f));
        }
}

// ---------- adapter GEMM2: z = t0 @ w_up^T, (4096 x 2048), K=64 ----------
__global__ __launch_bounds__(256, 2)
void k_adp2(const u16* __restrict__ t0, const u16* __restrict__ wu, float* __restrict__ z) {
    const int tid = threadIdx.x, wv = tid >> 6, l = tid & 63;
    const int m0 = blockIdx.x * 64 + wv * 16;
    const int n0 = blockIdx.y * 128;
    const int ko = (l >> 4) * 8;
    const bf16x8 a0 = load8(t0 + (size_t)(m0 + (l & 15)) * 64 + ko);
    const bf16x8 a1 = load8(t0 + (size_t)(m0 + (l & 15)) * 64 + 32 + ko);
#pragma unroll
    for (int ni = 0; ni < 8; ++ni) {
        const int n = n0 + ni * 16;
        const bf16x8 b0 = load8(wu + (size_t)(n + (l & 15)) * 64 + ko);
        const bf16x8 b1 = load8(wu + (size_t)(n + (l & 15)) * 64 + 32 + ko);
        f32x4 c = {0.f, 0.f, 0.f, 0.f};
        c = mfma16(a0, b0, c);
        c = mfma16(a1, b1, c);
#pragma unroll
        for (int r = 0; r < 4; ++r)
            z[(size_t)(m0 + (l >> 4) * 4 + r) * 2048 + n + (l & 15)] = c[r];
    }
}

// ---------- LayerNorm over 2048, optional bf16 output ----------
template <int BF16OUT>
__global__ __launch_bounds__(256, 4)
void k_ln(const float* __restrict__ z, const float* __restrict__ g,
          const float* __restrict__ be, void* __restrict__ out) {
    const int row = blockIdx.x, tid = threadIdx.x;
    const float* zr = z + (size_t)row * 2048;
    const float4 v0 = ((const float4*)zr)[tid * 2];
    const float4 v1 = ((const float4*)zr)[tid * 2 + 1];
    float o[8] = {v0.x, v0.y, v0.z, v0.w, v1.x, v1.y, v1.z, v1.w};
    float s = 0.f, q = 0.f;
#pragma unroll
    for (int i = 0; i < 8; ++i) { s += o[i]; q += o[i] * o[i]; }
#pragma unroll
    for (int off = 32; off > 0; off >>= 1) { s += __shfl_xor(s, off); q += __shfl_xor(q, off); }
    __shared__ float sm[8];
    const int wv = tid >> 6;
    if ((tid & 63) == 0) { sm[wv] = s; sm[4 + wv] = q; }
    __syncthreads();
    const float stot = sm[0] + sm[1] + sm[2] + sm[3];
    const float qtot = sm[4] + sm[5] + sm[6] + sm[7];
    const float mean = stot * (1.f / 2048.f);
    const float var = qtot * (1.f / 2048.f) - mean * mean;
    const float rs = rsqrtf(var + 1e-5f);
    const int c = tid * 8;
#pragma unroll
    for (int i = 0; i < 8; ++i) o[i] = (o[i] - mean) * rs * g[c + i] + be[c + i];
    if (BF16OUT) {
        u16* ob = (u16*)out + (size_t)row * 2048 + c;
#pragma unroll
        for (int i = 0; i < 8; ++i) ob[i] = f2bf(o[i]);
    } else {
        float* of = (float*)out + (size_t)row * 2048 + c;
        ((float4*)of)[0] = make_float4(o[0], o[1], o[2], o[3]);
        ((float4*)of)[1] = make_float4(o[4], o[5], o[6], o[7]);
    }
}

// ---------- host ----------
static inline void cvt_launch(const float* src, u16* dst, int n, hipStream_t s) {
    const int n4 = n / 4;
    k_cvt<<<(n4 + 255) / 256, 256, 0, s>>>(src, dst, n4);
}

extern "C" void kernel_launch(void* const* d_in, const int* in_sizes, int n_in,
                              void* d_out, int out_size, void* d_ws, size_t ws_size,
                              hipStream_t stream) {
    const float* x     = (const float*)d_in[0];
    const float* lemb  = (const float*)d_in[1];
    const float* hw    = (const float*)d_in[2];
    const float* wih0f = (const float*)d_in[3];
    const float* whh0f = (const float*)d_in[4];
    const float* bih0f = (const float*)d_in[5];
    const float* bhh0f = (const float*)d_in[6];
    const float* wih0r = (const float*)d_in[7];
    const float* whh0r = (const float*)d_in[8];
    const float* bih0r = (const float*)d_in[9];
    const float* bhh0r = (const float*)d_in[10];
    const float* lng0  = (const float*)d_in[11];
    const float* lnb0  = (const float*)d_in[12];
    const float* wih1f = (const float*)d_in[13];
    const float* whh1f = (const float*)d_in[14];
    const float* bih1f = (const float*)d_in[15];
    const float* bhh1f = (const float*)d_in[16];
    const float* wih1r = (const float*)d_in[17];
    const float* whh1r = (const float*)d_in[18];
    const float* bih1r = (const float*)d_in[19];
    const float* bhh1r = (const float*)d_in[20];
    const float* lng1  = (const float*)d_in[21];
    const float* lnb1  = (const float*)d_in[22];
    const int*   lid   = (const int*)d_in[23];

    char* ws = (char*)d_ws;
    u16* p_params = (u16*)(ws + O_PARAMS);
    u16* p_xbf    = (u16*)(ws + O_XBF);
    u16* p_wih0f  = (u16*)(ws + O_WIH0F);
    u16* p_wih0r  = (u16*)(ws + O_WIH0R);
    u16* p_wih1f  = (u16*)(ws + O_WIH1F);
    u16* p_wih1r  = (u16*)(ws + O_WIH1R);
    u16* p_whh0f  = (u16*)(ws + O_WHH0F);
    u16* p_whh0r  = (u16*)(ws + O_WHH0R);
    u16* p_whh1f  = (u16*)(ws + O_WHH1F);
    u16* p_whh1r  = (u16*)(ws + O_WHH1R);
    u16* p_xg     = (u16*)(ws + O_XG);
    u16* p_y      = (u16*)(ws + O_Y);
    u16* p_x1     = (u16*)(ws + O_X1);
    u16* p_t0     = (u16*)(ws + O_T0);
    u16* p_hbuf   = (u16*)(ws + O_HBUF);
    float* p_h0s  = (float*)(ws + O_H0S);
    float* p_c0s  = (float*)(ws + O_C0S);
    float* p_z    = (float*)(ws + O_XG);   // overlays Xg (dead when z is live)
    u32* p_sync0  = (u32*)(ws + O_SYNC);         // [2][128] u32
    u32* p_sync1  = (u32*)(ws + O_SYNC + 1024);  // [2][128] u32

    float* outx = (float*)d_out;
    float* outh = outx + 8 * 512 * 2048;
    float* outc = outh + 2 * 8 * 1024;

    // 1. hypernetwork params -> bf16 adapters
    k_params<<<2048, 256, 0, stream>>>(hw, lemb, lid, p_params);
    // 2. conversions to bf16
    cvt_launch(x, p_xbf, 4194304, stream);
    cvt_launch(wih0f, p_wih0f, 4194304, stream);
    cvt_launch(wih0r, p_wih0r, 4194304, stream);
    cvt_launch(wih1f, p_wih1f, 8388608, stream);
    cvt_launch(wih1r, p_wih1r, 8388608, stream);
    cvt_launch(whh0f, p_whh0f, 4194304, stream);
    cvt_launch(whh0r, p_whh0r, 4194304, stream);
    cvt_launch(whh1f, p_whh1f, 4194304, stream);
    cvt_launch(whh1r, p_whh1r, 4194304, stream);

    // 3. layer 0 input projections (f and r)
    k_gemm_xg<1024><<<dim3(32, 32), 256, 0, stream>>>(p_xbf, p_wih0f, bih0f, bhh0f, p_xg);
    k_gemm_xg<1024><<<dim3(32, 32), 256, 0, stream>>>(p_xbf, p_wih0r, bih0r, bhh0r, p_xg + 16777216);

    // 3b. zero barrier flags (xbf region is dead from here on; ws is 0xAA-poisoned
    //     each call, so this memset is mandatory every launch)
    hipMemsetAsync((void*)(ws + O_SYNC), 0, 2048, stream);

    // 4. layer 0 recurrence (cooperative launch for guaranteed co-residency)
    {
        const u16* xg_c = p_xg; const u16* wf = p_whh0f; const u16* wr = p_whh0r;
        const float* h0p = p_h0s; const float* c0p = p_c0s; int has = 0;
        u16* hb = p_hbuf; u16* yy = p_y; float* hf = p_h0s; float* cf = p_c0s;
        u32* sy = p_sync0;
        void* args[] = {&xg_c, &wf, &wr, &h0p, &c0p, &has, &hb, &yy, &hf, &cf, &sy};
        hipLaunchCooperativeKernel((void*)k_lstm, dim3(256), dim3(256), args, 0, stream);
    }

    // 5. adapter 0 + LN -> x1 (bf16)
    k_adp1<<<256, 64, 0, stream>>>(p_y, p_params, p_t0);
    k_adp2<<<dim3(64, 16), 256, 0, stream>>>(p_t0, p_params + 131072, p_z);
    k_ln<1><<<4096, 256, 0, stream>>>(p_z, lng0, lnb0, (void*)p_x1);

    // 6. layer 1 input projections
    k_gemm_xg<2048><<<dim3(32, 32), 256, 0, stream>>>(p_x1, p_wih1f, bih1f, bhh1f, p_xg);
    k_gemm_xg<2048><<<dim3(32, 32), 256, 0, stream>>>(p_x1, p_wih1r, bih1r, bhh1r, p_xg + 16777216);

    // 7. layer 1 recurrence (initial state = layer 0 finals), finals -> d_out
    {
        const u16* xg_c = p_xg; const u16* wf = p_whh1f; const u16* wr = p_whh1r;
        const float* h0p = p_h0s; const float* c0p = p_c0s; int has = 1;
        u16* hb = p_hbuf; u16* yy = p_y; float* hf = outh; float* cf = outc;
        u32* sy = p_sync1;
        void* args[] = {&xg_c, &wf, &wr, &h0p, &c0p, &has, &hb, &yy, &hf, &cf, &sy};
        hipLaunchCooperativeKernel((void*)k_lstm, dim3(256), dim3(256), args, 0, stream);
    }

    // 8. adapter 1 + LN -> d_out x (f32)
    k_adp1<<<256, 64, 0, stream>>>(p_y, p_params + 262144, p_t0);
    k_adp2<<<dim3(64, 16), 256, 0, stream>>>(p_t0, p_params + 262144 + 131072, p_z);
    k_ln<0><<<4096, 256, 0, stream>>>(p_z, lng1, lnb1, (void*)outx);
}